// Round 9
// baseline (149.810 us; speedup 1.0000x reference)
//
#include <hip/hip_runtime.h>
#include <hip/hip_bf16.h>

typedef __hip_bfloat16 bf16;
typedef __attribute__((ext_vector_type(8))) short bf16x8;
typedef __attribute__((ext_vector_type(4))) float f32x4;
typedef __attribute__((ext_vector_type(4))) unsigned int u32x4;

#define MFMA_BF16(a, b, c) __builtin_amdgcn_mfma_f32_16x16x32_bf16((a), (b), (c), 0, 0, 0)

static constexpr int B_  = 2;
static constexpr int S_  = 2048;
static constexpr int DM_ = 1024;
static constexpr int H_  = 16;
static constexpr int D_  = 64;
static constexpr int M_  = B_ * S_;   // 4096 rows for all GEMMs

__device__ __forceinline__ void load16(const void* g, void* l) {
  __builtin_amdgcn_global_load_lds(
      (const __attribute__((address_space(1))) void*)g,
      (__attribute__((address_space(3))) void*)l, 16, 0, 0);
}

__device__ __forceinline__ unsigned int pack_bf16(float lo, float hi) {
  const unsigned int ul = __builtin_bit_cast(unsigned short, __float2bfloat16(lo));
  const unsigned int uh = __builtin_bit_cast(unsigned short, __float2bfloat16(hi));
  return (uh << 16) | ul;
}

// ---------------- prep kernels ----------------

__global__ void cvt_f32_bf16_kernel(const float* __restrict__ in,
                                    bf16* __restrict__ out, int n4) {
  int i = blockIdx.x * blockDim.x + threadIdx.x;
  if (i >= n4) return;
  float4 v = ((const float4*)in)[i];
  ushort4 u;
  u.x = __builtin_bit_cast(unsigned short, __float2bfloat16(v.x));
  u.y = __builtin_bit_cast(unsigned short, __float2bfloat16(v.y));
  u.z = __builtin_bit_cast(unsigned short, __float2bfloat16(v.z));
  u.w = __builtin_bit_cast(unsigned short, __float2bfloat16(v.w));
  ((ushort4*)out)[i] = u;
}

// out[n][k] = (bf16) in[k][n], 1024x1024 ; blockIdx.z selects which W
__global__ void transpose_cvt_kernel(const float* __restrict__ w0,
                                     const float* __restrict__ w1,
                                     const float* __restrict__ w2,
                                     const float* __restrict__ w3,
                                     bf16* __restrict__ o0, bf16* __restrict__ o1,
                                     bf16* __restrict__ o2, bf16* __restrict__ o3) {
  __shared__ float t[32][33];
  const float* in = blockIdx.z == 0 ? w0 : blockIdx.z == 1 ? w1 : blockIdx.z == 2 ? w2 : w3;
  bf16* out = blockIdx.z == 0 ? o0 : blockIdx.z == 1 ? o1 : blockIdx.z == 2 ? o2 : o3;
  int tx = threadIdx.x & 31;
  int ty = threadIdx.x >> 5;  // 0..7
  int r0 = blockIdx.y * 32;
  int c0 = blockIdx.x * 32;
#pragma unroll
  for (int yy = 0; yy < 32; yy += 8)
    t[ty + yy][tx] = in[(size_t)(r0 + ty + yy) * DM_ + c0 + tx];
  __syncthreads();
#pragma unroll
  for (int yy = 0; yy < 32; yy += 8)
    out[(size_t)(c0 + ty + yy) * DM_ + r0 + tx] = __float2bfloat16(t[tx][ty + yy]);
}

// ---------------- 256^2 8-phase QKV GEMM (T2+T3+T4+T5) ----------------
// C = A(4096x1024) * Wqkv(3072x1024)^T + bias. 512 thr = 8 waves (2Mx4N),
// BM=BN=256, BK=64, 128KB dbuf LDS, row-XOR swizzle, counted vmcnt(2),
// 4 quadrant-phases per K-step with raw barriers + setprio.
// Output scatter: proj 0/1 (Q,K) -> (B,H,S,D) bf16; proj 2 (V) -> (B,H,D,S).
__global__ __launch_bounds__(512, 2) void gemm256_qkv_kernel(
    const bf16* __restrict__ A, const bf16* __restrict__ Bt,
    const float* __restrict__ bias, const float* __restrict__ bias2,
    const float* __restrict__ bias3, bf16* __restrict__ out) {
  __shared__ bf16 As[2][256 * 64];
  __shared__ bf16 Bs[2][256 * 64];
  const int tid = threadIdx.x;
  const int wid = tid >> 6, lane = tid & 63;
  const int g = lane >> 4, c = lane & 15;
  const int wr = wid >> 2, wc = wid & 3;   // 2M x 4N waves, each owns 128x64

  // bijective XCD swizzle (192 % 8 == 0): each XCD gets 24 contiguous wgids
  const int orig = blockIdx.x;
  const int wgid = (orig & 7) * 24 + (orig >> 3);
  const int bm = wgid & 15, bn = wgid >> 4;   // 16 x 12

  const char* Ag = (const char*)(A + (size_t)bm * 256 * 1024);
  const char* Bg = (const char*)(Bt + (size_t)bn * 256 * 1024);

  f32x4 acc[8][4] = {};

  // stage part pp (0..3) of K-step kt into buffer bufi: 2 x 16B per thread.
  // k 0..3 -> A (s = tid + k*512), k 4..7 -> B. Source seg pre-swizzled.
  auto stage2 = [&](int kt, int bufi, int pp) {
#pragma unroll
    for (int l = 0; l < 2; ++l) {
      const int k = pp * 2 + l;
      const int s = tid + (k & 3) * 512;          // 0..2047
      const int sr = s >> 3;                      // row 0..255
      const int sq = ((s & 7) ^ (sr & 7)) << 4;   // swizzled byte in row
      if (k < 4)
        load16(Ag + (size_t)sr * 2048 + kt * 128 + sq, (char*)As[bufi] + s * 16);
      else
        load16(Bg + (size_t)sr * 2048 + kt * 128 + sq, (char*)Bs[bufi] + s * 16);
    }
  };

  // prologue: stage K-step 0 fully into buf 0
#pragma unroll
  for (int pp = 0; pp < 4; ++pp) stage2(0, 0, pp);

  const int c7 = c & 7;
  int cur = 0;
#pragma unroll 1
  for (int kt = 0; kt < 16; ++kt) {
    if (kt < 15) {
      stage2(kt + 1, cur ^ 1, 0);
      asm volatile("s_waitcnt vmcnt(2)" ::: "memory");  // cur's 8 loads landed
    } else {
      asm volatile("s_waitcnt vmcnt(0)" ::: "memory");
    }
    __builtin_amdgcn_s_barrier();

#pragma unroll
    for (int p = 0; p < 4; ++p) {
      const int qr = p >> 1, qc = p & 1;
      // quadrant fragment loads (8 A + 4 B ds_read_b128, swizzled)
      bf16x8 af[4][2], bfr[2][2];
#pragma unroll
      for (int mi = 0; mi < 4; ++mi) {
        const int rb = (wr * 128 + qr * 64 + mi * 16 + c) * 128;
#pragma unroll
        for (int kk = 0; kk < 2; ++kk)
          af[mi][kk] = *(const bf16x8*)((const char*)As[cur] + rb +
                                        (((kk * 4 + g) ^ c7) << 4));
      }
#pragma unroll
      for (int ni = 0; ni < 2; ++ni) {
        const int rb = (wc * 64 + qc * 32 + ni * 16 + c) * 128;
#pragma unroll
        for (int kk = 0; kk < 2; ++kk)
          bfr[ni][kk] = *(const bf16x8*)((const char*)Bs[cur] + rb +
                                         (((kk * 4 + g) ^ c7) << 4));
      }
      if (p < 3 && kt < 15) stage2(kt + 1, cur ^ 1, p + 1);
      __builtin_amdgcn_s_barrier();
      __builtin_amdgcn_s_setprio(1);
#pragma unroll
      for (int mi = 0; mi < 4; ++mi)
#pragma unroll
        for (int ni = 0; ni < 2; ++ni)
#pragma unroll
          for (int kk = 0; kk < 2; ++kk)
            acc[qr * 4 + mi][qc * 2 + ni] =
                MFMA_BF16(af[mi][kk], bfr[ni][kk], acc[qr * 4 + mi][qc * 2 + ni]);
      __builtin_amdgcn_s_setprio(0);
      __builtin_amdgcn_s_barrier();
    }
    cur ^= 1;
  }

  // epilogue: C row = g*4 + rr (per frag), col = c
#pragma unroll
  for (int ni = 0; ni < 4; ++ni) {
    const int n_g = bn * 256 + wc * 64 + ni * 16 + c;
    const int proj = n_g >> 10, ncol = n_g & 1023;
    const float bv = proj == 0 ? bias[ncol] : proj == 1 ? bias2[ncol] : bias3[ncol];
    const int h = ncol >> 6, d = ncol & (D_ - 1);
#pragma unroll
    for (int mi = 0; mi < 8; ++mi) {
#pragma unroll
      for (int rr = 0; rr < 4; ++rr) {
        const int m_g = bm * 256 + wr * 128 + mi * 16 + g * 4 + rr;
        const float val = acc[mi][ni][rr] + bv;
        const int b = m_g >> 11, s = m_g & (S_ - 1);
        size_t idx = (size_t)proj * 4194304;
        if (proj < 2)
          idx += (((size_t)(b * H_ + h)) * S_ + s) * D_ + d;
        else
          idx += (((size_t)(b * H_ + h)) * D_ + d) * S_ + s;
        out[idx] = __float2bfloat16(val);
      }
    }
  }
}

// ---------------- 128^2 2-phase GEMM (output projection) ----------------
// fp32 out to (M, 1024).
__global__ __launch_bounds__(256) void gemm_bt_kernel(
    const bf16* __restrict__ A, const bf16* __restrict__ Bt,
    const float* __restrict__ bias, float* __restrict__ out, int K) {
  __shared__ bf16 As[2][128 * 32];
  __shared__ bf16 Bs[2][128 * 32];
  const int tid = threadIdx.x;
  const int wid = tid >> 6, lane = tid & 63;
  const int g = lane >> 4, c = lane & 15;
  const int wr = wid >> 1, wc = wid & 1;  // wave = 64x64 subtile
  const int bm = blockIdx.x, bn = blockIdx.y;

  f32x4 acc[4][4] = {};

  const char* Ag = (const char*)(A + (size_t)bm * 128 * K);
  const char* Bg = (const char*)(Bt + (size_t)bn * 128 * K);
  const int f0 = tid * 16, f1 = f0 + 4096;
  const int r0 = f0 >> 6, cb0 = f0 & 63;
  const int r1 = f1 >> 6;
  const size_t rowbytes = (size_t)K * 2;

  auto stage = [&](int kt, int bufi) {
    const size_t koff = (size_t)kt * 64;  // 32 bf16 = 64B
    load16(Ag + (size_t)r0 * rowbytes + koff + cb0, (char*)As[bufi] + f0);
    load16(Ag + (size_t)r1 * rowbytes + koff + cb0, (char*)As[bufi] + f1);
    load16(Bg + (size_t)r0 * rowbytes + koff + cb0, (char*)Bs[bufi] + f0);
    load16(Bg + (size_t)r1 * rowbytes + koff + cb0, (char*)Bs[bufi] + f1);
  };

  const int NT = K / 32;
  stage(0, 0);
  int cur = 0;
#pragma unroll 1
  for (int kt = 0; kt < NT; ++kt) {
    if (kt + 1 < NT) {
      stage(kt + 1, cur ^ 1);
      asm volatile("s_waitcnt vmcnt(4)" ::: "memory");  // own stage(kt) done
    } else {
      asm volatile("s_waitcnt vmcnt(0)" ::: "memory");
    }
    __builtin_amdgcn_s_barrier();   // all waves' stage(kt) landed

    bf16x8 af[4], bfr[4];
#pragma unroll
    for (int mi = 0; mi < 4; ++mi)
      af[mi] = *(const bf16x8*)&As[cur][(wr * 64 + mi * 16 + c) * 32 + g * 8];
#pragma unroll
    for (int ni = 0; ni < 4; ++ni)
      bfr[ni] = *(const bf16x8*)&Bs[cur][(wc * 64 + ni * 16 + c) * 32 + g * 8];
    __builtin_amdgcn_s_setprio(1);
#pragma unroll
    for (int mi = 0; mi < 4; ++mi)
#pragma unroll
      for (int ni = 0; ni < 4; ++ni)
        acc[mi][ni] = MFMA_BF16(af[mi], bfr[ni], acc[mi][ni]);
    __builtin_amdgcn_s_setprio(0);

    if (kt + 1 < NT) __builtin_amdgcn_s_barrier();  // reads of cur done before
    cur ^= 1;                                       // stage(kt+2) overwrites it
  }

#pragma unroll
  for (int ni = 0; ni < 4; ++ni) {
    const int n_g = bn * 128 + wc * 64 + ni * 16 + c;
    const float bv = bias[n_g];
#pragma unroll
    for (int mi = 0; mi < 4; ++mi) {
#pragma unroll
      for (int r = 0; r < 4; ++r) {
        const int m_g = bm * 128 + wr * 64 + mi * 16 + g * 4 + r;
        out[(size_t)m_g * DM_ + n_g] = acc[mi][ni][r] + bv;
      }
    }
  }
}

// ---------------- flash attention (proven R5/R6 kernel, unchanged) --------
// Q,K: (B,H,S,D) bf16 ; Vt: (B,H,D,S) bf16 ; Aout: (B,S,H*D) bf16
// Block = 4 waves = one t-quad of one bh; double-buffered swizzled LDS,
// depth-1 prefetch; swapped-QK^T in-register softmax.
__global__ __launch_bounds__(256, 4) void flash_attn_kernel(
    const bf16* __restrict__ Q, const bf16* __restrict__ Kg,
    const bf16* __restrict__ Vt, bf16* __restrict__ Aout) {
  __shared__ bf16 Ks[2][64 * 64];
  __shared__ bf16 Vs[2][64 * 64];
  const int tid = threadIdx.x;
  const int w = tid >> 6, lane = tid & 63;
  const int g = lane >> 4, c = lane & 15;

  const int bid = blockIdx.x;
  const int xcd = bid & 7, loc = bid >> 3;
  const int bh = xcd * 4 + (loc & 3);
  const int j = 31 - (loc >> 2);
  const int t = j * 4 + w;
  const int b = bh >> 4, h = bh & (H_ - 1);

  const float ALPHA2 = 0.125f * 1.44269504f;
  const float THR2 = 11.5f;
  const float NEG_INF = -__builtin_inff();

  const char* Kbase = (const char*)(Kg + (size_t)bh * S_ * D_);
  const char* Vbase = (const char*)(Vt + (size_t)bh * D_ * S_);
  const int s0 = tid, s1 = tid + 256;
  const int sr0 = s0 >> 3, sq0 = ((s0 & 7) ^ (sr0 & 7)) << 4;
  const int sr1 = s1 >> 3, sq1 = ((s1 & 7) ^ (sr1 & 7)) << 4;

  const bf16* Qp = Q + ((size_t)bh * S_ + t * 16 + c) * D_;
  bf16x8 qf[2];
  qf[0] = *(const bf16x8*)&Qp[g * 8];
  qf[1] = *(const bf16x8*)&Qp[32 + g * 8];

  f32x4 o[4] = {};
  float m = -1000.0f;
  float lsum = 0.0f;

  const int rowlim = w * 16 + c;
  const int src0 = ((g & 1) * 2) * 16 + c;
  const int src1 = src0 + 16;
  const bool ghi = (g >= 2);
  const int cs = c & 7;
  int roff[2][4];
#pragma unroll
  for (int kk = 0; kk < 2; ++kk)
#pragma unroll
    for (int n = 0; n < 4; ++n)
      roff[kk][n] = n * 2048 + c * 128 + (((kk * 4 + g) ^ cs) << 4);

  {
    load16(Kbase + sr0 * 128 + sq0, (char*)Ks[0] + s0 * 16);
    load16(Kbase + sr1 * 128 + sq1, (char*)Ks[0] + s1 * 16);
    load16(Vbase + sr0 * 4096 + sq0, (char*)Vs[0] + s0 * 16);
    load16(Vbase + sr1 * 4096 + sq1, (char*)Vs[0] + s1 * 16);
  }
  __syncthreads();

  int cur = 0;
#pragma unroll 1
  for (int kv = 0; kv <= j; ++kv) {
    if (kv < j) {
      const char* Krow = Kbase + (size_t)(kv + 1) * 8192;
      const char* Vcol = Vbase + (size_t)(kv + 1) * 128;
      const int nb = cur ^ 1;
      load16(Krow + sr0 * 128 + sq0, (char*)Ks[nb] + s0 * 16);
      load16(Krow + sr1 * 128 + sq1, (char*)Ks[nb] + s1 * 16);
      load16(Vcol + sr0 * 4096 + sq0, (char*)Vs[nb] + s0 * 16);
      load16(Vcol + sr1 * 4096 + sq1, (char*)Vs[nb] + s1 * 16);
    }

    const char* Kt = (const char*)Ks[cur];
    const char* Vtile = (const char*)Vs[cur];
    bf16x8 kf[2][4];
#pragma unroll
    for (int kk = 0; kk < 2; ++kk)
#pragma unroll
      for (int n = 0; n < 4; ++n)
        kf[kk][n] = *(const bf16x8*)(Kt + roff[kk][n]);

    f32x4 st[4] = {};
    __builtin_amdgcn_s_setprio(1);
#pragma unroll
    for (int n = 0; n < 4; ++n) {
      st[n] = MFMA_BF16(kf[0][n], qf[0], st[n]);
      st[n] = MFMA_BF16(kf[1][n], qf[1], st[n]);
    }
    __builtin_amdgcn_s_setprio(0);

    bf16x8 vf[2][4];
#pragma unroll
    for (int kk = 0; kk < 2; ++kk)
#pragma unroll
      for (int n = 0; n < 4; ++n)
        vf[kk][n] = *(const bf16x8*)(Vtile + roff[kk][n]);

    float aa[4][4];
#pragma unroll
    for (int n = 0; n < 4; ++n)
#pragma unroll
      for (int r = 0; r < 4; ++r)
        aa[n][r] = fmaf(st[n][r], ALPHA2, -m);
    if (kv == j) {
#pragma unroll
      for (int n = 0; n < 4; ++n)
#pragma unroll
        for (int r = 0; r < 4; ++r)
          if (n * 16 + g * 4 + r > rowlim) aa[n][r] = NEG_INF;
    }

    float dm;
    {
      float t0 = fmaxf(fmaxf(aa[0][0], aa[0][1]), fmaxf(aa[0][2], aa[0][3]));
      float t1 = fmaxf(fmaxf(aa[1][0], aa[1][1]), fmaxf(aa[1][2], aa[1][3]));
      float t2 = fmaxf(fmaxf(aa[2][0], aa[2][1]), fmaxf(aa[2][2], aa[2][3]));
      float t3 = fmaxf(fmaxf(aa[3][0], aa[3][1]), fmaxf(aa[3][2], aa[3][3]));
      dm = fmaxf(fmaxf(t0, t1), fmaxf(t2, t3));
    }
    dm = fmaxf(dm, __shfl_xor(dm, 16, 64));
    dm = fmaxf(dm, __shfl_xor(dm, 32, 64));

    if (__any(dm > THR2)) {
      const float sh = fmaxf(dm, 0.0f);
      const float sc = __builtin_amdgcn_exp2f(-sh);
      m += sh;
      lsum *= sc;
#pragma unroll
      for (int n = 0; n < 4; ++n)
#pragma unroll
        for (int r = 0; r < 4; ++r) o[n][r] *= sc;
#pragma unroll
      for (int n = 0; n < 4; ++n)
#pragma unroll
        for (int r = 0; r < 4; ++r) aa[n][r] -= sh;
    }

    float p[4][4];
#pragma unroll
    for (int n = 0; n < 4; ++n)
#pragma unroll
      for (int r = 0; r < 4; ++r) p[n][r] = __builtin_amdgcn_exp2f(aa[n][r]);
    {
      float q0 = (p[0][0] + p[0][1]) + (p[0][2] + p[0][3]);
      float q1 = (p[1][0] + p[1][1]) + (p[1][2] + p[1][3]);
      float q2 = (p[2][0] + p[2][1]) + (p[2][2] + p[2][3]);
      float q3 = (p[3][0] + p[3][1]) + (p[3][2] + p[3][3]);
      lsum += (q0 + q1) + (q2 + q3);
    }

    unsigned int dw[4][2];
#pragma unroll
    for (int n = 0; n < 4; ++n) {
      dw[n][0] = pack_bf16(p[n][0], p[n][1]);
      dw[n][1] = pack_bf16(p[n][2], p[n][3]);
    }

#pragma unroll
    for (int kk = 0; kk < 2; ++kk) {
      unsigned int bb[4];
      {
        unsigned int lo = __shfl(dw[kk * 2][0], src0, 64);
        unsigned int hi = __shfl(dw[kk * 2 + 1][0], src0, 64);
        bb[0] = ghi ? hi : lo;
      }
      {
        unsigned int lo = __shfl(dw[kk * 2][1], src0, 64);
        unsigned int hi = __shfl(dw[kk * 2 + 1][1], src0, 64);
        bb[1] = ghi ? hi : lo;
      }
      {
        unsigned int lo = __shfl(dw[kk * 2][0], src1, 64);
        unsigned int hi = __shfl(dw[kk * 2 + 1][0], src1, 64);
        bb[2] = ghi ? hi : lo;
      }
      {
        unsigned int lo = __shfl(dw[kk * 2][1], src1, 64);
        unsigned int hi = __shfl(dw[kk * 2 + 1][1], src1, 64);
        bb[3] = ghi ? hi : lo;
      }
      u32x4 bbv = {bb[0], bb[1], bb[2], bb[3]};
      bf16x8 pb = __builtin_bit_cast(bf16x8, bbv);
      __builtin_amdgcn_s_setprio(1);
#pragma unroll
      for (int n = 0; n < 4; ++n) o[n] = MFMA_BF16(vf[kk][n], pb, o[n]);
      __builtin_amdgcn_s_setprio(0);
    }

    __syncthreads();
    cur ^= 1;
  }

  lsum += __shfl_xor(lsum, 16, 64);
  lsum += __shfl_xor(lsum, 32, 64);
  const float inv = 1.0f / lsum;

  bf16* Arow = Aout + ((size_t)b * S_ + t * 16 + c) * (H_ * D_) + h * D_;
#pragma unroll
  for (int n = 0; n < 4; ++n) {
    ushort4 u;
    u.x = __builtin_bit_cast(unsigned short, __float2bfloat16(o[n][0] * inv));
    u.y = __builtin_bit_cast(unsigned short, __float2bfloat16(o[n][1] * inv));
    u.z = __builtin_bit_cast(unsigned short, __float2bfloat16(o[n][2] * inv));
    u.w = __builtin_bit_cast(unsigned short, __float2bfloat16(o[n][3] * inv));
    *(ushort4*)&Arow[n * 16 + g * 4] = u;
  }
}

// ---------------- launcher ----------------

extern "C" void kernel_launch(void* const* d_in, const int* in_sizes, int n_in,
                              void* d_out, int out_size, void* d_ws, size_t ws_size,
                              hipStream_t stream) {
  (void)in_sizes; (void)n_in; (void)out_size; (void)ws_size;
  const float* x  = (const float*)d_in[0];
  const float* Wq = (const float*)d_in[1];
  const float* bq = (const float*)d_in[2];
  const float* Wk = (const float*)d_in[3];
  const float* bk = (const float*)d_in[4];
  const float* Wv = (const float*)d_in[5];
  const float* bv = (const float*)d_in[6];
  const float* Wo = (const float*)d_in[7];
  const float* bo = (const float*)d_in[8];
  float* out = (float*)d_out;

  char* ws = (char*)d_ws;
  bf16* xb  = (bf16*)(ws);                    // 8 MB  (4096x1024 bf16)
  bf16* Wqt = (bf16*)(ws + (8u << 20));       // 2 MB each, CONTIGUOUS (QKV fused)
  bf16* Wkt = (bf16*)(ws + (10u << 20));
  bf16* Wvt = (bf16*)(ws + (12u << 20));
  bf16* Wot = (bf16*)(ws + (14u << 20));
  bf16* Qb  = (bf16*)(ws + (16u << 20));      // 8 MB  (B,H,S,D)  -- +0*4194304
  bf16* Kb  = (bf16*)(ws + (24u << 20));      // 8 MB             -- +1*4194304
  bf16* Vtb = (bf16*)(ws + (32u << 20));      // 8 MB  (B,H,D,S)  -- +2*4194304
  bf16* Ab  = xb;  // attention out reuses xb (xb dead after projections)

  cvt_f32_bf16_kernel<<<4096, 256, 0, stream>>>(x, xb, (M_ * DM_) / 4);
  transpose_cvt_kernel<<<dim3(32, 32, 4), 256, 0, stream>>>(
      Wq, Wk, Wv, Wo, Wqt, Wkt, Wvt, Wot);

  // fused QKV projection: Bt = [Wqt;Wkt;Wvt] (3072 rows), 256^2 8-phase
  gemm256_qkv_kernel<<<dim3(192), 512, 0, stream>>>(
      xb, Wqt, bq, bk, bv, Qb);

  flash_attn_kernel<<<dim3(1024), 256, 0, stream>>>(Qb, Kb, Vtb, Ab);

  gemm_bt_kernel<<<dim3(32, 8), 256, 0, stream>>>(Ab, Wot, bo, out, DM_);
}

// Round 10
// 123.453 us; speedup vs baseline: 1.2135x; 1.2135x over previous
//
#include <hip/hip_runtime.h>
#include <hip/hip_bf16.h>

typedef __hip_bfloat16 bf16;
typedef __attribute__((ext_vector_type(8))) short bf16x8;
typedef __attribute__((ext_vector_type(4))) float f32x4;
typedef __attribute__((ext_vector_type(4))) unsigned int u32x4;

#define MFMA_BF16(a, b, c) __builtin_amdgcn_mfma_f32_16x16x32_bf16((a), (b), (c), 0, 0, 0)

static constexpr int B_  = 2;
static constexpr int S_  = 2048;
static constexpr int DM_ = 1024;
static constexpr int H_  = 16;
static constexpr int D_  = 64;
static constexpr int M_  = B_ * S_;   // 4096 rows for all GEMMs

__device__ __forceinline__ void load16(const void* g, void* l) {
  __builtin_amdgcn_global_load_lds(
      (const __attribute__((address_space(1))) void*)g,
      (__attribute__((address_space(3))) void*)l, 16, 0, 0);
}

__device__ __forceinline__ unsigned int pack_bf16(float lo, float hi) {
  const unsigned int ul = __builtin_bit_cast(unsigned short, __float2bfloat16(lo));
  const unsigned int uh = __builtin_bit_cast(unsigned short, __float2bfloat16(hi));
  return (uh << 16) | ul;
}

// ---------------- prep kernels ----------------

__global__ void cvt_f32_bf16_kernel(const float* __restrict__ in,
                                    bf16* __restrict__ out, int n4) {
  int i = blockIdx.x * blockDim.x + threadIdx.x;
  if (i >= n4) return;
  float4 v = ((const float4*)in)[i];
  ushort4 u;
  u.x = __builtin_bit_cast(unsigned short, __float2bfloat16(v.x));
  u.y = __builtin_bit_cast(unsigned short, __float2bfloat16(v.y));
  u.z = __builtin_bit_cast(unsigned short, __float2bfloat16(v.z));
  u.w = __builtin_bit_cast(unsigned short, __float2bfloat16(v.w));
  ((ushort4*)out)[i] = u;
}

// out[n][k] = (bf16) in[k][n], 1024x1024 ; blockIdx.z selects which W
__global__ void transpose_cvt_kernel(const float* __restrict__ w0,
                                     const float* __restrict__ w1,
                                     const float* __restrict__ w2,
                                     const float* __restrict__ w3,
                                     bf16* __restrict__ o0, bf16* __restrict__ o1,
                                     bf16* __restrict__ o2, bf16* __restrict__ o3) {
  __shared__ float t[32][33];
  const float* in = blockIdx.z == 0 ? w0 : blockIdx.z == 1 ? w1 : blockIdx.z == 2 ? w2 : w3;
  bf16* out = blockIdx.z == 0 ? o0 : blockIdx.z == 1 ? o1 : blockIdx.z == 2 ? o2 : o3;
  int tx = threadIdx.x & 31;
  int ty = threadIdx.x >> 5;  // 0..7
  int r0 = blockIdx.y * 32;
  int c0 = blockIdx.x * 32;
#pragma unroll
  for (int yy = 0; yy < 32; yy += 8)
    t[ty + yy][tx] = in[(size_t)(r0 + ty + yy) * DM_ + c0 + tx];
  __syncthreads();
#pragma unroll
  for (int yy = 0; yy < 32; yy += 8)
    out[(size_t)(c0 + ty + yy) * DM_ + r0 + tx] = __float2bfloat16(t[tx][ty + yy]);
}

// ---------------- GEMM: C = A(MxK) * Bt(NxK)^T + bias ----------------
// Minimum 2-phase pipeline (T3 recipe): double-buffered LDS, stage(kt+1)
// issued at iter top, counted vmcnt(4) + raw barriers, no vmcnt(0) mid-loop.
// MODE 2: store fp32 to (M, 1024)                 (output projection)
// MODE 3: fused QKV: Bt has 3072 rows (Wq;Wk;Wv). Q,K -> (B,H,S,D) bf16,
//         V -> (B,H,D,S) bf16, at out + proj*4194304 elems.
template <int MODE>
__global__ __launch_bounds__(256) void gemm_bt_kernel(
    const bf16* __restrict__ A, const bf16* __restrict__ Bt,
    const float* __restrict__ bias, const float* __restrict__ bias2,
    const float* __restrict__ bias3, void* __restrict__ out, int K) {
  __shared__ bf16 As[2][128 * 32];
  __shared__ bf16 Bs[2][128 * 32];
  const int tid = threadIdx.x;
  const int wid = tid >> 6, lane = tid & 63;
  const int g = lane >> 4, c = lane & 15;
  const int wr = wid >> 1, wc = wid & 1;  // wave = 64x64 subtile
  const int bm = blockIdx.x, bn = blockIdx.y;

  f32x4 acc[4][4] = {};

  const char* Ag = (const char*)(A + (size_t)bm * 128 * K);
  const char* Bg = (const char*)(Bt + (size_t)bn * 128 * K);
  const int f0 = tid * 16, f1 = f0 + 4096;
  const int r0 = f0 >> 6, cb0 = f0 & 63;
  const int r1 = f1 >> 6;
  const size_t rowbytes = (size_t)K * 2;

  auto stage = [&](int kt, int bufi) {
    const size_t koff = (size_t)kt * 64;  // 32 bf16 = 64B
    load16(Ag + (size_t)r0 * rowbytes + koff + cb0, (char*)As[bufi] + f0);
    load16(Ag + (size_t)r1 * rowbytes + koff + cb0, (char*)As[bufi] + f1);
    load16(Bg + (size_t)r0 * rowbytes + koff + cb0, (char*)Bs[bufi] + f0);
    load16(Bg + (size_t)r1 * rowbytes + koff + cb0, (char*)Bs[bufi] + f1);
  };

  const int NT = K / 32;
  stage(0, 0);
  int cur = 0;
#pragma unroll 1
  for (int kt = 0; kt < NT; ++kt) {
    if (kt + 1 < NT) {
      stage(kt + 1, cur ^ 1);
      asm volatile("s_waitcnt vmcnt(4)" ::: "memory");  // own stage(kt) done
    } else {
      asm volatile("s_waitcnt vmcnt(0)" ::: "memory");
    }
    __builtin_amdgcn_s_barrier();   // all waves' stage(kt) landed

    bf16x8 af[4], bfr[4];
#pragma unroll
    for (int mi = 0; mi < 4; ++mi)
      af[mi] = *(const bf16x8*)&As[cur][(wr * 64 + mi * 16 + c) * 32 + g * 8];
#pragma unroll
    for (int ni = 0; ni < 4; ++ni)
      bfr[ni] = *(const bf16x8*)&Bs[cur][(wc * 64 + ni * 16 + c) * 32 + g * 8];
    __builtin_amdgcn_s_setprio(1);
#pragma unroll
    for (int mi = 0; mi < 4; ++mi)
#pragma unroll
      for (int ni = 0; ni < 4; ++ni)
        acc[mi][ni] = MFMA_BF16(af[mi], bfr[ni], acc[mi][ni]);
    __builtin_amdgcn_s_setprio(0);

    if (kt + 1 < NT) __builtin_amdgcn_s_barrier();  // reads of cur done before
    cur ^= 1;                                       // stage(kt+2) overwrites it
  }

  // epilogue: C row = (lane>>4)*4 + r, col = lane&15  (per 16x16 frag)
#pragma unroll
  for (int ni = 0; ni < 4; ++ni) {
    const int n_g = bn * 128 + wc * 64 + ni * 16 + c;
    float bv;
    if constexpr (MODE == 3) {
      const int proj = n_g >> 10, ncol = n_g & 1023;
      bv = proj == 0 ? bias[ncol] : proj == 1 ? bias2[ncol] : bias3[ncol];
    } else {
      bv = bias[n_g];
    }
#pragma unroll
    for (int mi = 0; mi < 4; ++mi) {
#pragma unroll
      for (int r = 0; r < 4; ++r) {
        const int m_g = bm * 128 + wr * 64 + mi * 16 + g * 4 + r;
        const float val = acc[mi][ni][r] + bv;
        if constexpr (MODE == 2) {
          ((float*)out)[(size_t)m_g * DM_ + n_g] = val;
        } else {
          const int proj = n_g >> 10, ncol = n_g & 1023;
          const int b = m_g >> 11, s = m_g & (S_ - 1);
          const int h = ncol >> 6, d = ncol & (D_ - 1);
          size_t idx = (size_t)proj * 4194304;
          if (proj < 2)
            idx += (((size_t)(b * H_ + h)) * S_ + s) * D_ + d;
          else
            idx += (((size_t)(b * H_ + h)) * D_ + d) * S_ + s;
          ((bf16*)out)[idx] = __float2bfloat16(val);
        }
      }
    }
  }
}

// ---------------- flash attention ----------------
// Q,K: (B,H,S,D) bf16 ; Vt: (B,H,D,S) bf16 ; Aout: (B,S,H*D) bf16
// Block = 4 waves = one t-quad of one bh; double-buffered XOR-swizzled LDS.
// R9 change (only): counted-vmcnt pipeline — stage(kv+1) stays in flight
// across the barrier (vmcnt(4), never 0 mid-loop), two raw barriers per iter
// instead of __syncthreads' full drain. Wave body unchanged from R6.
__global__ __launch_bounds__(256, 4) void flash_attn_kernel(
    const bf16* __restrict__ Q, const bf16* __restrict__ Kg,
    const bf16* __restrict__ Vt, bf16* __restrict__ Aout) {
  __shared__ bf16 Ks[2][64 * 64];
  __shared__ bf16 Vs[2][64 * 64];
  const int tid = threadIdx.x;
  const int w = tid >> 6, lane = tid & 63;
  const int g = lane >> 4, c = lane & 15;

  const int bid = blockIdx.x;
  const int xcd = bid & 7, loc = bid >> 3;
  const int bh = xcd * 4 + (loc & 3);
  const int j = 31 - (loc >> 2);
  const int t = j * 4 + w;
  const int b = bh >> 4, h = bh & (H_ - 1);

  const float ALPHA2 = 0.125f * 1.44269504f;
  const float THR2 = 11.5f;
  const float NEG_INF = -__builtin_inff();

  const char* Kbase = (const char*)(Kg + (size_t)bh * S_ * D_);
  const char* Vbase = (const char*)(Vt + (size_t)bh * D_ * S_);
  const int s0 = tid, s1 = tid + 256;
  const int sr0 = s0 >> 3, sq0 = ((s0 & 7) ^ (sr0 & 7)) << 4;
  const int sr1 = s1 >> 3, sq1 = ((s1 & 7) ^ (sr1 & 7)) << 4;

  auto stageKV = [&](int kv, int bufi) {
    const char* Krow = Kbase + (size_t)kv * 8192;   // 64 rows * 128B
    const char* Vcol = Vbase + (size_t)kv * 128;
    load16(Krow + sr0 * 128 + sq0, (char*)Ks[bufi] + s0 * 16);
    load16(Krow + sr1 * 128 + sq1, (char*)Ks[bufi] + s1 * 16);
    load16(Vcol + sr0 * 4096 + sq0, (char*)Vs[bufi] + s0 * 16);
    load16(Vcol + sr1 * 4096 + sq1, (char*)Vs[bufi] + s1 * 16);
  };

  const bf16* Qp = Q + ((size_t)bh * S_ + t * 16 + c) * D_;
  bf16x8 qf[2];
  qf[0] = *(const bf16x8*)&Qp[g * 8];
  qf[1] = *(const bf16x8*)&Qp[32 + g * 8];

  f32x4 o[4] = {};
  float m = -1000.0f;
  float lsum = 0.0f;

  const int rowlim = w * 16 + c;
  const int src0 = ((g & 1) * 2) * 16 + c;
  const int src1 = src0 + 16;
  const bool ghi = (g >= 2);
  const int cs = c & 7;
  int roff[2][4];
#pragma unroll
  for (int kk = 0; kk < 2; ++kk)
#pragma unroll
    for (int n = 0; n < 4; ++n)
      roff[kk][n] = n * 2048 + c * 128 + (((kk * 4 + g) ^ cs) << 4);

  stageKV(0, 0);

  int cur = 0;
#pragma unroll 1
  for (int kv = 0; kv <= j; ++kv) {
    // issue next-tile staging; own stage(kv) must land, stage(kv+1) stays
    // in flight across the barrier (counted vmcnt, never 0 mid-loop)
    if (kv < j) {
      stageKV(kv + 1, cur ^ 1);
      asm volatile("s_waitcnt vmcnt(4)" ::: "memory");
    } else {
      asm volatile("s_waitcnt vmcnt(0)" ::: "memory");
    }
    __builtin_amdgcn_s_barrier();   // all waves' stage(kv) landed

    // ---- compute on buffer cur ----
    const char* Kt = (const char*)Ks[cur];
    const char* Vtile = (const char*)Vs[cur];
    bf16x8 kf[2][4];
#pragma unroll
    for (int kk = 0; kk < 2; ++kk)
#pragma unroll
      for (int n = 0; n < 4; ++n)
        kf[kk][n] = *(const bf16x8*)(Kt + roff[kk][n]);

    f32x4 st[4] = {};
    __builtin_amdgcn_s_setprio(1);
#pragma unroll
    for (int n = 0; n < 4; ++n) {
      st[n] = MFMA_BF16(kf[0][n], qf[0], st[n]);
      st[n] = MFMA_BF16(kf[1][n], qf[1], st[n]);
    }
    __builtin_amdgcn_s_setprio(0);

    bf16x8 vf[2][4];
#pragma unroll
    for (int kk = 0; kk < 2; ++kk)
#pragma unroll
      for (int n = 0; n < 4; ++n)
        vf[kk][n] = *(const bf16x8*)(Vtile + roff[kk][n]);

    float aa[4][4];
#pragma unroll
    for (int n = 0; n < 4; ++n)
#pragma unroll
      for (int r = 0; r < 4; ++r)
        aa[n][r] = fmaf(st[n][r], ALPHA2, -m);
    if (kv == j) {
#pragma unroll
      for (int n = 0; n < 4; ++n)
#pragma unroll
        for (int r = 0; r < 4; ++r)
          if (n * 16 + g * 4 + r > rowlim) aa[n][r] = NEG_INF;
    }

    float dm;
    {
      float t0 = fmaxf(fmaxf(aa[0][0], aa[0][1]), fmaxf(aa[0][2], aa[0][3]));
      float t1 = fmaxf(fmaxf(aa[1][0], aa[1][1]), fmaxf(aa[1][2], aa[1][3]));
      float t2 = fmaxf(fmaxf(aa[2][0], aa[2][1]), fmaxf(aa[2][2], aa[2][3]));
      float t3 = fmaxf(fmaxf(aa[3][0], aa[3][1]), fmaxf(aa[3][2], aa[3][3]));
      dm = fmaxf(fmaxf(t0, t1), fmaxf(t2, t3));
    }
    dm = fmaxf(dm, __shfl_xor(dm, 16, 64));
    dm = fmaxf(dm, __shfl_xor(dm, 32, 64));

    if (__any(dm > THR2)) {
      const float sh = fmaxf(dm, 0.0f);
      const float sc = __builtin_amdgcn_exp2f(-sh);
      m += sh;
      lsum *= sc;
#pragma unroll
      for (int n = 0; n < 4; ++n)
#pragma unroll
        for (int r = 0; r < 4; ++r) o[n][r] *= sc;
#pragma unroll
      for (int n = 0; n < 4; ++n)
#pragma unroll
        for (int r = 0; r < 4; ++r) aa[n][r] -= sh;
    }

    float p[4][4];
#pragma unroll
    for (int n = 0; n < 4; ++n)
#pragma unroll
      for (int r = 0; r < 4; ++r) p[n][r] = __builtin_amdgcn_exp2f(aa[n][r]);
    {
      float q0 = (p[0][0] + p[0][1]) + (p[0][2] + p[0][3]);
      float q1 = (p[1][0] + p[1][1]) + (p[1][2] + p[1][3]);
      float q2 = (p[2][0] + p[2][1]) + (p[2][2] + p[2][3]);
      float q3 = (p[3][0] + p[3][1]) + (p[3][2] + p[3][3]);
      lsum += (q0 + q1) + (q2 + q3);
    }

    unsigned int dw[4][2];
#pragma unroll
    for (int n = 0; n < 4; ++n) {
      dw[n][0] = pack_bf16(p[n][0], p[n][1]);
      dw[n][1] = pack_bf16(p[n][2], p[n][3]);
    }

#pragma unroll
    for (int kk = 0; kk < 2; ++kk) {
      unsigned int bb[4];
      {
        unsigned int lo = __shfl(dw[kk * 2][0], src0, 64);
        unsigned int hi = __shfl(dw[kk * 2 + 1][0], src0, 64);
        bb[0] = ghi ? hi : lo;
      }
      {
        unsigned int lo = __shfl(dw[kk * 2][1], src0, 64);
        unsigned int hi = __shfl(dw[kk * 2 + 1][1], src0, 64);
        bb[1] = ghi ? hi : lo;
      }
      {
        unsigned int lo = __shfl(dw[kk * 2][0], src1, 64);
        unsigned int hi = __shfl(dw[kk * 2 + 1][0], src1, 64);
        bb[2] = ghi ? hi : lo;
      }
      {
        unsigned int lo = __shfl(dw[kk * 2][1], src1, 64);
        unsigned int hi = __shfl(dw[kk * 2 + 1][1], src1, 64);
        bb[3] = ghi ? hi : lo;
      }
      u32x4 bbv = {bb[0], bb[1], bb[2], bb[3]};
      bf16x8 pb = __builtin_bit_cast(bf16x8, bbv);
      __builtin_amdgcn_s_setprio(1);
#pragma unroll
      for (int n = 0; n < 4; ++n) o[n] = MFMA_BF16(vf[kk][n], pb, o[n]);
      __builtin_amdgcn_s_setprio(0);
    }

    // all waves done reading buf cur before next iter's stage overwrites it
    if (kv < j) __builtin_amdgcn_s_barrier();
    cur ^= 1;
  }

  lsum += __shfl_xor(lsum, 16, 64);
  lsum += __shfl_xor(lsum, 32, 64);
  const float inv = 1.0f / lsum;

  bf16* Arow = Aout + ((size_t)b * S_ + t * 16 + c) * (H_ * D_) + h * D_;
#pragma unroll
  for (int n = 0; n < 4; ++n) {
    ushort4 u;
    u.x = __builtin_bit_cast(unsigned short, __float2bfloat16(o[n][0] * inv));
    u.y = __builtin_bit_cast(unsigned short, __float2bfloat16(o[n][1] * inv));
    u.z = __builtin_bit_cast(unsigned short, __float2bfloat16(o[n][2] * inv));
    u.w = __builtin_bit_cast(unsigned short, __float2bfloat16(o[n][3] * inv));
    *(ushort4*)&Arow[n * 16 + g * 4] = u;
  }
}

// ---------------- launcher ----------------

extern "C" void kernel_launch(void* const* d_in, const int* in_sizes, int n_in,
                              void* d_out, int out_size, void* d_ws, size_t ws_size,
                              hipStream_t stream) {
  (void)in_sizes; (void)n_in; (void)out_size; (void)ws_size;
  const float* x  = (const float*)d_in[0];
  const float* Wq = (const float*)d_in[1];
  const float* bq = (const float*)d_in[2];
  const float* Wk = (const float*)d_in[3];
  const float* bk = (const float*)d_in[4];
  const float* Wv = (const float*)d_in[5];
  const float* bv = (const float*)d_in[6];
  const float* Wo = (const float*)d_in[7];
  const float* bo = (const float*)d_in[8];
  float* out = (float*)d_out;

  char* ws = (char*)d_ws;
  bf16* xb  = (bf16*)(ws);                    // 8 MB  (4096x1024 bf16)
  bf16* Wqt = (bf16*)(ws + (8u << 20));       // 2 MB each, CONTIGUOUS (QKV fused)
  bf16* Wkt = (bf16*)(ws + (10u << 20));
  bf16* Wvt = (bf16*)(ws + (12u << 20));
  bf16* Wot = (bf16*)(ws + (14u << 20));
  bf16* Qb  = (bf16*)(ws + (16u << 20));      // 8 MB  (B,H,S,D)  -- +0*4194304
  bf16* Kb  = (bf16*)(ws + (24u << 20));      // 8 MB             -- +1*4194304
  bf16* Vtb = (bf16*)(ws + (32u << 20));      // 8 MB  (B,H,D,S)  -- +2*4194304
  bf16* Ab  = xb;  // attention out reuses xb (xb dead after projections)

  cvt_f32_bf16_kernel<<<4096, 256, 0, stream>>>(x, xb, (M_ * DM_) / 4);
  transpose_cvt_kernel<<<dim3(32, 32, 4), 256, 0, stream>>>(
      Wq, Wk, Wv, Wo, Wqt, Wkt, Wvt, Wot);

  // fused QKV projection: Bt = [Wqt;Wkt;Wvt] (3072 rows), 2-phase 128^2
  gemm_bt_kernel<3><<<dim3(32, 24), 256, 0, stream>>>(
      xb, Wqt, bq, bk, bv, (void*)Qb, DM_);

  flash_attn_kernel<<<dim3(1024), 256, 0, stream>>>(Qb, Kb, Vtb, Ab);

  gemm_bt_kernel<2><<<dim3(32, 8), 256, 0, stream>>>(
      Ab, Wot, bo, nullptr, nullptr, (void*)out, DM_);
}

// Round 11
// 118.719 us; speedup vs baseline: 1.2619x; 1.0399x over previous
//
#include <hip/hip_runtime.h>
#include <hip/hip_bf16.h>

typedef __hip_bfloat16 bf16;
typedef __attribute__((ext_vector_type(8))) short bf16x8;
typedef __attribute__((ext_vector_type(4))) float f32x4;
typedef __attribute__((ext_vector_type(4))) unsigned int u32x4;

#define MFMA_BF16(a, b, c) __builtin_amdgcn_mfma_f32_16x16x32_bf16((a), (b), (c), 0, 0, 0)

static constexpr int B_  = 2;
static constexpr int S_  = 2048;
static constexpr int DM_ = 1024;
static constexpr int H_  = 16;
static constexpr int D_  = 64;
static constexpr int M_  = B_ * S_;   // 4096 rows for all GEMMs

__device__ __forceinline__ void load16(const void* g, void* l) {
  __builtin_amdgcn_global_load_lds(
      (const __attribute__((address_space(1))) void*)g,
      (__attribute__((address_space(3))) void*)l, 16, 0, 0);
}

__device__ __forceinline__ unsigned int pack_bf16(float lo, float hi) {
  const unsigned int ul = __builtin_bit_cast(unsigned short, __float2bfloat16(lo));
  const unsigned int uh = __builtin_bit_cast(unsigned short, __float2bfloat16(hi));
  return (uh << 16) | ul;
}

// ---------------- prep kernels ----------------

__global__ void cvt_f32_bf16_kernel(const float* __restrict__ in,
                                    bf16* __restrict__ out, int n4) {
  int i = blockIdx.x * blockDim.x + threadIdx.x;
  if (i >= n4) return;
  float4 v = ((const float4*)in)[i];
  ushort4 u;
  u.x = __builtin_bit_cast(unsigned short, __float2bfloat16(v.x));
  u.y = __builtin_bit_cast(unsigned short, __float2bfloat16(v.y));
  u.z = __builtin_bit_cast(unsigned short, __float2bfloat16(v.z));
  u.w = __builtin_bit_cast(unsigned short, __float2bfloat16(v.w));
  ((ushort4*)out)[i] = u;
}

// out[n][k] = (bf16) in[k][n], 1024x1024 ; blockIdx.z selects which W
__global__ void transpose_cvt_kernel(const float* __restrict__ w0,
                                     const float* __restrict__ w1,
                                     const float* __restrict__ w2,
                                     const float* __restrict__ w3,
                                     bf16* __restrict__ o0, bf16* __restrict__ o1,
                                     bf16* __restrict__ o2, bf16* __restrict__ o3) {
  __shared__ float t[32][33];
  const float* in = blockIdx.z == 0 ? w0 : blockIdx.z == 1 ? w1 : blockIdx.z == 2 ? w2 : w3;
  bf16* out = blockIdx.z == 0 ? o0 : blockIdx.z == 1 ? o1 : blockIdx.z == 2 ? o2 : o3;
  int tx = threadIdx.x & 31;
  int ty = threadIdx.x >> 5;  // 0..7
  int r0 = blockIdx.y * 32;
  int c0 = blockIdx.x * 32;
#pragma unroll
  for (int yy = 0; yy < 32; yy += 8)
    t[ty + yy][tx] = in[(size_t)(r0 + ty + yy) * DM_ + c0 + tx];
  __syncthreads();
#pragma unroll
  for (int yy = 0; yy < 32; yy += 8)
    out[(size_t)(c0 + ty + yy) * DM_ + r0 + tx] = __float2bfloat16(t[tx][ty + yy]);
}

// ---------------- GEMM: C = A(MxK) * Bt(NxK)^T + bias ----------------
// Minimum 2-phase pipeline (T3 recipe): double-buffered LDS, stage(kt+1)
// issued at iter top, counted vmcnt(4) + raw barriers, no vmcnt(0) mid-loop.
// MODE 2: store fp32 to (M, 1024)                 (output projection)
// MODE 3: fused QKV: Bt has 3072 rows (Wq;Wk;Wv). Q,K -> (B,H,S,D) bf16,
//         V -> (B,H,D,S) bf16, at out + proj*4194304 elems.
template <int MODE>
__global__ __launch_bounds__(256) void gemm_bt_kernel(
    const bf16* __restrict__ A, const bf16* __restrict__ Bt,
    const float* __restrict__ bias, const float* __restrict__ bias2,
    const float* __restrict__ bias3, void* __restrict__ out, int K) {
  __shared__ bf16 As[2][128 * 32];
  __shared__ bf16 Bs[2][128 * 32];
  const int tid = threadIdx.x;
  const int wid = tid >> 6, lane = tid & 63;
  const int g = lane >> 4, c = lane & 15;
  const int wr = wid >> 1, wc = wid & 1;  // wave = 64x64 subtile
  const int bm = blockIdx.x, bn = blockIdx.y;

  f32x4 acc[4][4] = {};

  const char* Ag = (const char*)(A + (size_t)bm * 128 * K);
  const char* Bg = (const char*)(Bt + (size_t)bn * 128 * K);
  const int f0 = tid * 16, f1 = f0 + 4096;
  const int r0 = f0 >> 6, cb0 = f0 & 63;
  const int r1 = f1 >> 6;
  const size_t rowbytes = (size_t)K * 2;

  auto stage = [&](int kt, int bufi) {
    const size_t koff = (size_t)kt * 64;  // 32 bf16 = 64B
    load16(Ag + (size_t)r0 * rowbytes + koff + cb0, (char*)As[bufi] + f0);
    load16(Ag + (size_t)r1 * rowbytes + koff + cb0, (char*)As[bufi] + f1);
    load16(Bg + (size_t)r0 * rowbytes + koff + cb0, (char*)Bs[bufi] + f0);
    load16(Bg + (size_t)r1 * rowbytes + koff + cb0, (char*)Bs[bufi] + f1);
  };

  const int NT = K / 32;
  stage(0, 0);
  int cur = 0;
#pragma unroll 1
  for (int kt = 0; kt < NT; ++kt) {
    if (kt + 1 < NT) {
      stage(kt + 1, cur ^ 1);
      asm volatile("s_waitcnt vmcnt(4)" ::: "memory");  // own stage(kt) done
    } else {
      asm volatile("s_waitcnt vmcnt(0)" ::: "memory");
    }
    __builtin_amdgcn_s_barrier();   // all waves' stage(kt) landed

    bf16x8 af[4], bfr[4];
#pragma unroll
    for (int mi = 0; mi < 4; ++mi)
      af[mi] = *(const bf16x8*)&As[cur][(wr * 64 + mi * 16 + c) * 32 + g * 8];
#pragma unroll
    for (int ni = 0; ni < 4; ++ni)
      bfr[ni] = *(const bf16x8*)&Bs[cur][(wc * 64 + ni * 16 + c) * 32 + g * 8];
    __builtin_amdgcn_s_setprio(1);
#pragma unroll
    for (int mi = 0; mi < 4; ++mi)
#pragma unroll
      for (int ni = 0; ni < 4; ++ni)
        acc[mi][ni] = MFMA_BF16(af[mi], bfr[ni], acc[mi][ni]);
    __builtin_amdgcn_s_setprio(0);

    if (kt + 1 < NT) __builtin_amdgcn_s_barrier();  // reads of cur done before
    cur ^= 1;                                       // stage(kt+2) overwrites it
  }

  // epilogue: C row = (lane>>4)*4 + r, col = lane&15  (per 16x16 frag)
#pragma unroll
  for (int ni = 0; ni < 4; ++ni) {
    const int n_g = bn * 128 + wc * 64 + ni * 16 + c;
    float bv;
    if constexpr (MODE == 3) {
      const int proj = n_g >> 10, ncol = n_g & 1023;
      bv = proj == 0 ? bias[ncol] : proj == 1 ? bias2[ncol] : bias3[ncol];
    } else {
      bv = bias[n_g];
    }
#pragma unroll
    for (int mi = 0; mi < 4; ++mi) {
#pragma unroll
      for (int r = 0; r < 4; ++r) {
        const int m_g = bm * 128 + wr * 64 + mi * 16 + g * 4 + r;
        const float val = acc[mi][ni][r] + bv;
        if constexpr (MODE == 2) {
          ((float*)out)[(size_t)m_g * DM_ + n_g] = val;
        } else {
          const int proj = n_g >> 10, ncol = n_g & 1023;
          const int b = m_g >> 11, s = m_g & (S_ - 1);
          const int h = ncol >> 6, d = ncol & (D_ - 1);
          size_t idx = (size_t)proj * 4194304;
          if (proj < 2)
            idx += (((size_t)(b * H_ + h)) * S_ + s) * D_ + d;
          else
            idx += (((size_t)(b * H_ + h)) * D_ + d) * S_ + s;
          ((bf16*)out)[idx] = __float2bfloat16(val);
        }
      }
    }
  }
}

// ---------------- flash attention ----------------
// Q,K: (B,H,S,D) bf16 ; Vt: (B,H,D,S) bf16 ; Aout: (B,S,H*D) bf16
// Block = 4 waves = one t-quad of one bh; double-buffered XOR-swizzled LDS
// (R6-proven __syncthreads pipeline). Swapped-QK^T in-register softmax.
// R10 change (only): rescale gate uses the per-lane local max (in-lane tree)
// so the two cross-lane shfl_xor + rescale work run only on the rare
// tile-max-growth path (T13 defer-max; validated numerically in R6-split).
__global__ __launch_bounds__(256, 4) void flash_attn_kernel(
    const bf16* __restrict__ Q, const bf16* __restrict__ Kg,
    const bf16* __restrict__ Vt, bf16* __restrict__ Aout) {
  __shared__ bf16 Ks[2][64 * 64];
  __shared__ bf16 Vs[2][64 * 64];
  const int tid = threadIdx.x;
  const int w = tid >> 6, lane = tid & 63;
  const int g = lane >> 4, c = lane & 15;

  const int bid = blockIdx.x;
  const int xcd = bid & 7, loc = bid >> 3;
  const int bh = xcd * 4 + (loc & 3);
  const int j = 31 - (loc >> 2);
  const int t = j * 4 + w;
  const int b = bh >> 4, h = bh & (H_ - 1);

  const float ALPHA2 = 0.125f * 1.44269504f;
  const float THR2 = 11.5f;
  const float NEG_INF = -__builtin_inff();

  const char* Kbase = (const char*)(Kg + (size_t)bh * S_ * D_);
  const char* Vbase = (const char*)(Vt + (size_t)bh * D_ * S_);
  const int s0 = tid, s1 = tid + 256;
  const int sr0 = s0 >> 3, sq0 = ((s0 & 7) ^ (sr0 & 7)) << 4;
  const int sr1 = s1 >> 3, sq1 = ((s1 & 7) ^ (sr1 & 7)) << 4;

  const bf16* Qp = Q + ((size_t)bh * S_ + t * 16 + c) * D_;
  bf16x8 qf[2];
  qf[0] = *(const bf16x8*)&Qp[g * 8];
  qf[1] = *(const bf16x8*)&Qp[32 + g * 8];

  f32x4 o[4] = {};
  float m = -1000.0f;
  float lsum = 0.0f;

  const int rowlim = w * 16 + c;
  const int src0 = ((g & 1) * 2) * 16 + c;
  const int src1 = src0 + 16;
  const bool ghi = (g >= 2);
  const int cs = c & 7;
  int roff[2][4];
#pragma unroll
  for (int kk = 0; kk < 2; ++kk)
#pragma unroll
    for (int n = 0; n < 4; ++n)
      roff[kk][n] = n * 2048 + c * 128 + (((kk * 4 + g) ^ cs) << 4);

  {
    load16(Kbase + sr0 * 128 + sq0, (char*)Ks[0] + s0 * 16);
    load16(Kbase + sr1 * 128 + sq1, (char*)Ks[0] + s1 * 16);
    load16(Vbase + sr0 * 4096 + sq0, (char*)Vs[0] + s0 * 16);
    load16(Vbase + sr1 * 4096 + sq1, (char*)Vs[0] + s1 * 16);
  }
  __syncthreads();

  int cur = 0;
#pragma unroll 1
  for (int kv = 0; kv <= j; ++kv) {
    if (kv < j) {
      const char* Krow = Kbase + (size_t)(kv + 1) * 8192;
      const char* Vcol = Vbase + (size_t)(kv + 1) * 128;
      const int nb = cur ^ 1;
      load16(Krow + sr0 * 128 + sq0, (char*)Ks[nb] + s0 * 16);
      load16(Krow + sr1 * 128 + sq1, (char*)Ks[nb] + s1 * 16);
      load16(Vcol + sr0 * 4096 + sq0, (char*)Vs[nb] + s0 * 16);
      load16(Vcol + sr1 * 4096 + sq1, (char*)Vs[nb] + s1 * 16);
    }

    const char* Kt = (const char*)Ks[cur];
    const char* Vtile = (const char*)Vs[cur];
    bf16x8 kf[2][4];
#pragma unroll
    for (int kk = 0; kk < 2; ++kk)
#pragma unroll
      for (int n = 0; n < 4; ++n)
        kf[kk][n] = *(const bf16x8*)(Kt + roff[kk][n]);

    f32x4 st[4] = {};
    __builtin_amdgcn_s_setprio(1);
#pragma unroll
    for (int n = 0; n < 4; ++n) {
      st[n] = MFMA_BF16(kf[0][n], qf[0], st[n]);
      st[n] = MFMA_BF16(kf[1][n], qf[1], st[n]);
    }
    __builtin_amdgcn_s_setprio(0);

    bf16x8 vf[2][4];
#pragma unroll
    for (int kk = 0; kk < 2; ++kk)
#pragma unroll
      for (int n = 0; n < 4; ++n)
        vf[kk][n] = *(const bf16x8*)(Vtile + roff[kk][n]);

    float aa[4][4];
#pragma unroll
    for (int n = 0; n < 4; ++n)
#pragma unroll
      for (int r = 0; r < 4; ++r)
        aa[n][r] = fmaf(st[n][r], ALPHA2, -m);
    if (kv == j) {
#pragma unroll
      for (int n = 0; n < 4; ++n)
#pragma unroll
        for (int r = 0; r < 4; ++r)
          if (n * 16 + g * 4 + r > rowlim) aa[n][r] = NEG_INF;
    }

    // per-lane local max only on the common path (in-lane 15-op tree);
    // cross-lane row-max + rescale only when growth exceeds THR2 (rare)
    float lm;
    {
      float t0 = fmaxf(fmaxf(aa[0][0], aa[0][1]), fmaxf(aa[0][2], aa[0][3]));
      float t1 = fmaxf(fmaxf(aa[1][0], aa[1][1]), fmaxf(aa[1][2], aa[1][3]));
      float t2 = fmaxf(fmaxf(aa[2][0], aa[2][1]), fmaxf(aa[2][2], aa[2][3]));
      float t3 = fmaxf(fmaxf(aa[3][0], aa[3][1]), fmaxf(aa[3][2], aa[3][3]));
      lm = fmaxf(fmaxf(t0, t1), fmaxf(t2, t3));
    }

    if (__any(lm > THR2)) {
      float dm = fmaxf(lm, __shfl_xor(lm, 16, 64));
      dm = fmaxf(dm, __shfl_xor(dm, 32, 64));   // row max across g-groups
      const float sh = fmaxf(dm, 0.0f);
      const float sc = __builtin_amdgcn_exp2f(-sh);
      m += sh;
      lsum *= sc;
#pragma unroll
      for (int n = 0; n < 4; ++n)
#pragma unroll
        for (int r = 0; r < 4; ++r) o[n][r] *= sc;
#pragma unroll
      for (int n = 0; n < 4; ++n)
#pragma unroll
        for (int r = 0; r < 4; ++r) aa[n][r] -= sh;
    }

    float p[4][4];
#pragma unroll
    for (int n = 0; n < 4; ++n)
#pragma unroll
      for (int r = 0; r < 4; ++r) p[n][r] = __builtin_amdgcn_exp2f(aa[n][r]);
    {
      float q0 = (p[0][0] + p[0][1]) + (p[0][2] + p[0][3]);
      float q1 = (p[1][0] + p[1][1]) + (p[1][2] + p[1][3]);
      float q2 = (p[2][0] + p[2][1]) + (p[2][2] + p[2][3]);
      float q3 = (p[3][0] + p[3][1]) + (p[3][2] + p[3][3]);
      lsum += (q0 + q1) + (q2 + q3);
    }

    unsigned int dw[4][2];
#pragma unroll
    for (int n = 0; n < 4; ++n) {
      dw[n][0] = pack_bf16(p[n][0], p[n][1]);
      dw[n][1] = pack_bf16(p[n][2], p[n][3]);
    }

#pragma unroll
    for (int kk = 0; kk < 2; ++kk) {
      unsigned int bb[4];
      {
        unsigned int lo = __shfl(dw[kk * 2][0], src0, 64);
        unsigned int hi = __shfl(dw[kk * 2 + 1][0], src0, 64);
        bb[0] = ghi ? hi : lo;
      }
      {
        unsigned int lo = __shfl(dw[kk * 2][1], src0, 64);
        unsigned int hi = __shfl(dw[kk * 2 + 1][1], src0, 64);
        bb[1] = ghi ? hi : lo;
      }
      {
        unsigned int lo = __shfl(dw[kk * 2][0], src1, 64);
        unsigned int hi = __shfl(dw[kk * 2 + 1][0], src1, 64);
        bb[2] = ghi ? hi : lo;
      }
      {
        unsigned int lo = __shfl(dw[kk * 2][1], src1, 64);
        unsigned int hi = __shfl(dw[kk * 2 + 1][1], src1, 64);
        bb[3] = ghi ? hi : lo;
      }
      u32x4 bbv = {bb[0], bb[1], bb[2], bb[3]};
      bf16x8 pb = __builtin_bit_cast(bf16x8, bbv);
      __builtin_amdgcn_s_setprio(1);
#pragma unroll
      for (int n = 0; n < 4; ++n) o[n] = MFMA_BF16(vf[kk][n], pb, o[n]);
      __builtin_amdgcn_s_setprio(0);
    }

    __syncthreads();
    cur ^= 1;
  }

  lsum += __shfl_xor(lsum, 16, 64);
  lsum += __shfl_xor(lsum, 32, 64);
  const float inv = 1.0f / lsum;

  bf16* Arow = Aout + ((size_t)b * S_ + t * 16 + c) * (H_ * D_) + h * D_;
#pragma unroll
  for (int n = 0; n < 4; ++n) {
    ushort4 u;
    u.x = __builtin_bit_cast(unsigned short, __float2bfloat16(o[n][0] * inv));
    u.y = __builtin_bit_cast(unsigned short, __float2bfloat16(o[n][1] * inv));
    u.z = __builtin_bit_cast(unsigned short, __float2bfloat16(o[n][2] * inv));
    u.w = __builtin_bit_cast(unsigned short, __float2bfloat16(o[n][3] * inv));
    *(ushort4*)&Arow[n * 16 + g * 4] = u;
  }
}

// ---------------- launcher ----------------

extern "C" void kernel_launch(void* const* d_in, const int* in_sizes, int n_in,
                              void* d_out, int out_size, void* d_ws, size_t ws_size,
                              hipStream_t stream) {
  (void)in_sizes; (void)n_in; (void)out_size; (void)ws_size;
  const float* x  = (const float*)d_in[0];
  const float* Wq = (const float*)d_in[1];
  const float* bq = (const float*)d_in[2];
  const float* Wk = (const float*)d_in[3];
  const float* bk = (const float*)d_in[4];
  const float* Wv = (const float*)d_in[5];
  const float* bv = (const float*)d_in[6];
  const float* Wo = (const float*)d_in[7];
  const float* bo = (const float*)d_in[8];
  float* out = (float*)d_out;

  char* ws = (char*)d_ws;
  bf16* xb  = (bf16*)(ws);                    // 8 MB  (4096x1024 bf16)
  bf16* Wqt = (bf16*)(ws + (8u << 20));       // 2 MB each, CONTIGUOUS (QKV fused)
  bf16* Wkt = (bf16*)(ws + (10u << 20));
  bf16* Wvt = (bf16*)(ws + (12u << 20));
  bf16* Wot = (bf16*)(ws + (14u << 20));
  bf16* Qb  = (bf16*)(ws + (16u << 20));      // 8 MB  (B,H,S,D)  -- +0*4194304
  bf16* Kb  = (bf16*)(ws + (24u << 20));      // 8 MB             -- +1*4194304
  bf16* Vtb = (bf16*)(ws + (32u << 20));      // 8 MB  (B,H,D,S)  -- +2*4194304
  bf16* Ab  = xb;  // attention out reuses xb (xb dead after projections)

  cvt_f32_bf16_kernel<<<4096, 256, 0, stream>>>(x, xb, (M_ * DM_) / 4);
  transpose_cvt_kernel<<<dim3(32, 32, 4), 256, 0, stream>>>(
      Wq, Wk, Wv, Wo, Wqt, Wkt, Wvt, Wot);

  // fused QKV projection: Bt = [Wqt;Wkt;Wvt] (3072 rows), 2-phase 128^2
  gemm_bt_kernel<3><<<dim3(32, 24), 256, 0, stream>>>(
      xb, Wqt, bq, bk, bv, (void*)Qb, DM_);

  flash_attn_kernel<<<dim3(1024), 256, 0, stream>>>(Qb, Kb, Vtb, Ab);

  gemm_bt_kernel<2><<<dim3(32, 8), 256, 0, stream>>>(
      Ab, Wot, bo, nullptr, nullptr, (void*)out, DM_);
}